// Round 3
// baseline (1430.122 us; speedup 1.0000x reference)
//
#include <hip/hip_runtime.h>
#include <cstdint>
#include <cstddef>

#define C_DIM 768
#define N_DIM 16384

typedef __attribute__((ext_vector_type(8)))  int   i32x8;
typedef __attribute__((ext_vector_type(4)))  int   i32x4;
typedef __attribute__((ext_vector_type(16))) float f32x16;

__device__ __forceinline__ void async_ld16(const void* g, void* l) {
    __builtin_amdgcn_global_load_lds(
        (__attribute__((address_space(1))) void*)g,
        (__attribute__((address_space(3))) void*)l,
        16, 0, 0);
}

// ---------------------------------------------------------------------------
// Normalize columns of F (C_DIM x N_DIM), write transposed fp8 e4m3:
// T[i][c] = fp8( 16 * F[c][i] / max(||col_i||, eps) ).  The x16 pre-scale
// (undone by the MFMA e8m0 scale 2^-4 per operand) keeps small components
// out of e4m3 subnormal range.  blockIdx.y selects the input.
// ---------------------------------------------------------------------------
__global__ __launch_bounds__(256) void norm_tr(const float* __restrict__ F0,
                                               unsigned char* __restrict__ T0,
                                               const float* __restrict__ F1,
                                               unsigned char* __restrict__ T1) {
    const float*   F = blockIdx.y ? F1 : F0;
    unsigned char* T = blockIdx.y ? T1 : T0;
    const int i0 = blockIdx.x * 64;
    const int t  = threadIdx.x;
    const int tx = t & 63;        // column within tile
    const int ty = t >> 6;        // 0..3

    // ---- phase 1: per-column sum of squares ----
    float ss = 0.f;
    for (int c = ty; c < C_DIM; c += 4) {
        float v = F[(size_t)c * N_DIM + i0 + tx];
        ss += v * v;
    }
    __shared__ float red[4][64];
    __shared__ float scale[64];
    red[ty][tx] = ss;
    __syncthreads();
    if (t < 64) {
        float s = red[0][t] + red[1][t] + red[2][t] + red[3][t];
        float n = sqrtf(s);
        scale[t] = 16.0f / fmaxf(n, 1e-12f);   // x16 folded in
    }
    __syncthreads();

    // ---- phase 2: transpose in 64x64 chunks, scaled, write fp8 ----
    __shared__ float tile[64][65];   // +1 pad: conflict-free
    const int i_l   = t >> 3;        // 0..31
    const int c_off = (t & 7) * 8;   // 0..56
    for (int c0 = 0; c0 < C_DIM; c0 += 64) {
        #pragma unroll
        for (int rr = 0; rr < 16; ++rr) {
            int c_l = rr * 4 + ty;
            tile[c_l][tx] = F[(size_t)(c0 + c_l) * N_DIM + i0 + tx] * scale[tx];
        }
        __syncthreads();
        #pragma unroll
        for (int half = 0; half < 2; ++half) {
            int il = i_l + half * 32;
            float v[8];
            #pragma unroll
            for (int j = 0; j < 8; ++j) v[j] = tile[c_off + j][il];
            int lo = __builtin_amdgcn_cvt_pk_fp8_f32(v[0], v[1], 0, false);
            lo     = __builtin_amdgcn_cvt_pk_fp8_f32(v[2], v[3], lo, true);
            int hi = __builtin_amdgcn_cvt_pk_fp8_f32(v[4], v[5], 0, false);
            hi     = __builtin_amdgcn_cvt_pk_fp8_f32(v[6], v[7], hi, true);
            uint2 u; u.x = (unsigned)lo; u.y = (unsigned)hi;
            *(uint2*)&T[(size_t)(i0 + il) * C_DIM + c0 + c_off] = u;
        }
        __syncthreads();
    }
}

// ---------------------------------------------------------------------------
// Fused GEMM + row-max over K=768, MX-fp8 (m148 path): 128x128 tile, BK=64,
// 4 waves x 2x2 of mfma_scale_f32_32x32x64_f8f6f4, scales = 2^-4 (byte 123).
// 12 K-iters (half of bf16), half the staging bytes, 2x MFMA rate.
//
// LDS: row-major [row][64B].  Staging thread t -> row t>>2, phys 16B chunk
// t&3, sourcing LOGICAL chunk (t&3)^((t>>3)&3) (round-2 verified swizzle,
// SQ_LDS_BANK_CONFLICT == 0).  Read side: lane's 32B logical k-group j
// (j=lane>>5) lives at 32B block j^((row>>2)&1), with 16B halves swapped
// when (row>>1)&1.
// ---------------------------------------------------------------------------
__global__ __launch_bounds__(256) void gemm_rowmax(const unsigned char* __restrict__ A,
                                                   const unsigned char* __restrict__ B,
                                                   unsigned* __restrict__ rowkey) {
    __shared__ __align__(16) unsigned char As[128 * 64];
    __shared__ __align__(16) unsigned char Bs[128 * 64];

    const int t    = threadIdx.x;
    const int lane = t & 63;
    const int w    = t >> 6;
    const int wm   = w >> 1, wn = w & 1;
    const int m0   = blockIdx.y * 128;
    const int n0   = blockIdx.x * 128;

    f32x16 acc[2][2];
    #pragma unroll
    for (int i = 0; i < 2; ++i)
        #pragma unroll
        for (int j = 0; j < 2; ++j)
            #pragma unroll
            for (int e = 0; e < 16; ++e)
                acc[i][j][e] = 0.f;

    // ---- staging addresses ----
    const int r    = t >> 2;
    const int clog = (t & 3) ^ ((t >> 3) & 3);
    const unsigned char* ag0 = A + (size_t)(m0 + r) * C_DIM + clog * 16;
    const unsigned char* ag1 = ag0 + (size_t)64 * C_DIM;
    const unsigned char* bg0 = B + (size_t)(n0 + r) * C_DIM + clog * 16;
    const unsigned char* bg1 = bg0 + (size_t)64 * C_DIM;
    unsigned char* asd0 = As + t * 16;
    unsigned char* asd1 = As + 4096 + t * 16;
    unsigned char* bsd0 = Bs + t * 16;
    unsigned char* bsd1 = Bs + 4096 + t * 16;

    // ---- fragment read offsets ----
    const int row = lane & 31;         // row within 32-subtile (base %32==0)
    const int j   = lane >> 5;         // k-half: logical 32B block index
    const int f   = (row >> 1) & 3;    // staging swizzle for this row
    const int bp  = j ^ (f >> 1);      // physical 32B block
    const int lo_off = bp * 32 + (f & 1) * 16;        // k 0..15 of lane chunk
    const int hi_off = bp * 32 + ((f & 1) ^ 1) * 16;  // k 16..31
    const int a_base0 = (wm * 64 +      row) * 64;
    const int a_base1 = (wm * 64 + 32 + row) * 64;
    const int b_base0 = (wn * 64 +      row) * 64;
    const int b_base1 = (wn * 64 + 32 + row) * 64;

    for (int k0 = 0; k0 < C_DIM; k0 += 64) {
        async_ld16(ag0 + k0, asd0);
        async_ld16(ag1 + k0, asd1);
        async_ld16(bg0 + k0, bsd0);
        async_ld16(bg1 + k0, bsd1);
        __syncthreads();

        i32x8 af[2], bf[2];
        {
            i32x4 lo, hi;
            lo = *(const i32x4*)(As + a_base0 + lo_off);
            hi = *(const i32x4*)(As + a_base0 + hi_off);
            af[0] = (i32x8){lo.x, lo.y, lo.z, lo.w, hi.x, hi.y, hi.z, hi.w};
            lo = *(const i32x4*)(As + a_base1 + lo_off);
            hi = *(const i32x4*)(As + a_base1 + hi_off);
            af[1] = (i32x8){lo.x, lo.y, lo.z, lo.w, hi.x, hi.y, hi.z, hi.w};
            lo = *(const i32x4*)(Bs + b_base0 + lo_off);
            hi = *(const i32x4*)(Bs + b_base0 + hi_off);
            bf[0] = (i32x8){lo.x, lo.y, lo.z, lo.w, hi.x, hi.y, hi.z, hi.w};
            lo = *(const i32x4*)(Bs + b_base1 + lo_off);
            hi = *(const i32x4*)(Bs + b_base1 + hi_off);
            bf[1] = (i32x8){lo.x, lo.y, lo.z, lo.w, hi.x, hi.y, hi.z, hi.w};
        }
        #pragma unroll
        for (int mi = 0; mi < 2; ++mi)
            #pragma unroll
            for (int ni = 0; ni < 2; ++ni)
                acc[mi][ni] = __builtin_amdgcn_mfma_scale_f32_32x32x64_f8f6f4(
                    af[mi], bf[ni], acc[mi][ni],
                    0, 0,                      // cbsz=FP8(e4m3), blgp=FP8(e4m3)
                    0, 0x7B7B7B7B,             // opsel_a, scale_a = 2^-4
                    0, 0x7B7B7B7B);            // opsel_b, scale_b = 2^-4
        __syncthreads();
    }

    // ---- epilogue: per-row max over this block's 128 columns ----
    // 32x32 C/D layout: col = lane&31, row = (reg&3) + 8*(reg>>2) + 4*(lane>>5)
    #pragma unroll
    for (int mi = 0; mi < 2; ++mi) {
        #pragma unroll
        for (int reg = 0; reg < 16; ++reg) {
            float v = fmaxf(acc[mi][0][reg], acc[mi][1][reg]);
            #pragma unroll
            for (int off = 1; off < 32; off <<= 1)
                v = fmaxf(v, __shfl_xor(v, off, 64));   // stays in 32-lane half
            if ((lane & 31) == 0) {
                int m = m0 + wm * 64 + mi * 32 + (reg & 3) + 8 * (reg >> 2)
                        + 4 * (lane >> 5);
                unsigned u = __float_as_uint(v);
                u = (u & 0x80000000u) ? ~u : (u | 0x80000000u);  // order-preserving
                atomicMax(&rowkey[m], u);
            }
        }
    }
}

// ---------------------------------------------------------------------------
// Final: loss = 1 - mean(rowmax)
// ---------------------------------------------------------------------------
__global__ __launch_bounds__(1024) void finalize(const unsigned* __restrict__ rowkey,
                                                 float* __restrict__ out) {
    const int t = threadIdx.x;
    float s = 0.f;
    for (int i = t; i < N_DIM; i += 1024) {
        unsigned u = rowkey[i];
        float f = (u & 0x80000000u) ? __uint_as_float(u ^ 0x80000000u)
                                    : __uint_as_float(~u);
        s += f;
    }
    #pragma unroll
    for (int off = 32; off >= 1; off >>= 1)
        s += __shfl_down(s, off, 64);
    __shared__ float part[16];
    if ((t & 63) == 0) part[t >> 6] = s;
    __syncthreads();
    if (t == 0) {
        float tot = 0.f;
        #pragma unroll
        for (int i = 0; i < 16; ++i) tot += part[i];
        out[0] = 1.0f - tot * (1.0f / (float)N_DIM);
    }
}

extern "C" void kernel_launch(void* const* d_in, const int* in_sizes, int n_in,
                              void* d_out, int out_size, void* d_ws, size_t ws_size,
                              hipStream_t stream) {
    const float* F_r = (const float*)d_in[0];
    const float* F_s = (const float*)d_in[1];

    unsigned char* Rt = (unsigned char*)d_ws;                 // 16384 x 768 fp8
    unsigned char* St = Rt + (size_t)N_DIM * C_DIM;           // 16384 x 768 fp8
    unsigned* rowkey  = (unsigned*)(St + (size_t)N_DIM * C_DIM);  // 16384 u32
    float*    out     = (float*)d_out;

    hipLaunchKernelGGL(norm_tr, dim3(N_DIM / 64, 2), dim3(256), 0, stream,
                       F_r, Rt, F_s, St);
    hipMemsetAsync(rowkey, 0, N_DIM * sizeof(unsigned), stream);
    hipLaunchKernelGGL(gemm_rowmax, dim3(N_DIM / 128, N_DIM / 128), dim3(256),
                       0, stream, Rt, St, rowkey);
    hipLaunchKernelGGL(finalize, dim3(1), dim3(1024), 0, stream, rowkey, out);
}

// Round 4
// 692.896 us; speedup vs baseline: 2.0640x; 2.0640x over previous
//
#include <hip/hip_runtime.h>
#include <cstdint>
#include <cstddef>

#define C_DIM 768
#define N_DIM 16384

typedef __attribute__((ext_vector_type(8))) short short8;   // 8 bf16 = 4 VGPRs
typedef __attribute__((ext_vector_type(4))) float f32x4;

__device__ __forceinline__ ushort f2bf(float f) {
    uint32_t u = __float_as_uint(f);
    uint32_t r = 0x7fffu + ((u >> 16) & 1u);   // round-to-nearest-even
    return (ushort)((u + r) >> 16);
}

__device__ __forceinline__ void async_ld16(const void* g, void* l) {
    __builtin_amdgcn_global_load_lds(
        (__attribute__((address_space(1))) void*)g,
        (__attribute__((address_space(3))) void*)l,
        16, 0, 0);
}

// ---------------------------------------------------------------------------
// Normalize columns of F (C_DIM x N_DIM) and write transposed bf16:
// T[i][c] = F[c][i] / max(||col_i||, eps).  blockIdx.y selects the input.
// (verified round 1/2)
// ---------------------------------------------------------------------------
__global__ __launch_bounds__(256) void norm_tr(const float* __restrict__ F0,
                                               ushort* __restrict__ T0,
                                               const float* __restrict__ F1,
                                               ushort* __restrict__ T1) {
    const float*  F = blockIdx.y ? F1 : F0;
    ushort*       T = blockIdx.y ? T1 : T0;
    const int i0 = blockIdx.x * 64;
    const int t  = threadIdx.x;
    const int tx = t & 63;
    const int ty = t >> 6;

    float ss = 0.f;
    for (int c = ty; c < C_DIM; c += 4) {
        float v = F[(size_t)c * N_DIM + i0 + tx];
        ss += v * v;
    }
    __shared__ float red[4][64];
    __shared__ float scale[64];
    red[ty][tx] = ss;
    __syncthreads();
    if (t < 64) {
        float s = red[0][t] + red[1][t] + red[2][t] + red[3][t];
        float n = sqrtf(s);
        scale[t] = 1.0f / fmaxf(n, 1e-12f);
    }
    __syncthreads();

    __shared__ float tile[64][65];
    const int i_l   = t >> 3;
    const int c_off = (t & 7) * 8;
    for (int c0 = 0; c0 < C_DIM; c0 += 64) {
        #pragma unroll
        for (int rr = 0; rr < 16; ++rr) {
            int c_l = rr * 4 + ty;
            tile[c_l][tx] = F[(size_t)(c0 + c_l) * N_DIM + i0 + tx] * scale[tx];
        }
        __syncthreads();
        #pragma unroll
        for (int half = 0; half < 2; ++half) {
            int il = i_l + half * 32;
            __align__(16) ushort pack[8];
            #pragma unroll
            for (int j = 0; j < 8; ++j)
                pack[j] = f2bf(tile[c_off + j][il]);
            *(uint4*)&T[(size_t)(i0 + il) * C_DIM + c0 + c_off] = *(const uint4*)pack;
        }
        __syncthreads();
    }
}

// ---------------------------------------------------------------------------
// Fused GEMM + row-max, round-2 verified core (bf16 16x16x32, 128x128 tile,
// BK=32, XOR LDS swizzle -> 0 bank conflicts) plus two latency attacks:
//
// 1) XCD-aware swizzle: grid is 1D; xcd = bid&7 owns a 1024-col n-slice
//    (8 n-tiles = 1.5 MB of B, resident in its 4 MB L2); n varies fastest
//    so A-tiles also get L2 reuse across 8 consecutive local blocks.
//    Staged loads then hit L2 (~200 cyc) instead of L3 (~500 cyc), which
//    sits directly inside the vmcnt(0) barrier drain.
// 2) Double-buffered LDS, ONE barrier per K-step: stage buf[k+1] right
//    after the iter-k barrier, compute from buf[k].  The vmcnt(0) drain at
//    barrier k+1 waits on loads that had the whole compute phase in flight.
// ---------------------------------------------------------------------------
__global__ __launch_bounds__(256) void gemm_rowmax(const ushort* __restrict__ A,
                                                   const ushort* __restrict__ B,
                                                   unsigned* __restrict__ rowkey) {
    __shared__ __align__(16) ushort As[2][128 * 32];
    __shared__ __align__(16) ushort Bs[2][128 * 32];

    const int t    = threadIdx.x;
    const int lane = t & 63;
    const int w    = t >> 6;
    const int wm   = w >> 1, wn = w & 1;

    // XCD-aware mapping: bid -> (m-tile, n-tile)
    const int bid   = blockIdx.x;
    const int xcd   = bid & 7;
    const int local = bid >> 3;          // 0..2047
    const int half_ = local >> 10;       // 0..1  (two 8-tile n-subslices)
    const int rem   = local & 1023;
    const int m0    = (rem >> 3) * 128;                        // 0..127 m-tiles
    const int n0    = (xcd * 16 + half_ * 8 + (rem & 7)) * 128; // n fastest

    f32x4 acc[4][4];
    #pragma unroll
    for (int i = 0; i < 4; ++i)
        #pragma unroll
        for (int j = 0; j < 4; ++j)
            acc[i][j] = (f32x4){0.f, 0.f, 0.f, 0.f};

    // staging: thread t -> row r = t>>2 (and r+64), LDS byte offset t*16.
    // logical k-quad sourced from global is XOR-swizzled by row bits 1-2.
    const int r  = t >> 2;
    const int kq = ((t & 3) ^ ((t >> 3) & 3)) * 8;
    const ushort* ag0 = A + (size_t)(m0 + r) * C_DIM + kq;
    const ushort* ag1 = ag0 + (size_t)64 * C_DIM;
    const ushort* bg0 = B + (size_t)(n0 + r) * C_DIM + kq;
    const ushort* bg1 = bg0 + (size_t)64 * C_DIM;
    const int ld0 = t * 8, ld1 = 64 * 32 + t * 8;

    // fragment read offsets: logical k-quad x = lane>>4 lives at
    // quadpos x ^ ((row>>1)&3); row = base + (lane&15), base % 16 == 0.
    const int qp    = ((lane >> 4) ^ ((lane >> 1) & 3)) * 8;
    const int a_off = (wm * 64 + (lane & 15)) * 32 + qp;
    const int b_off = (wn * 64 + (lane & 15)) * 32 + qp;

    // prologue: stage k0=0 into buffer 0
    async_ld16(ag0, As[0] + ld0);
    async_ld16(ag1, As[0] + ld1);
    async_ld16(bg0, Bs[0] + ld0);
    async_ld16(bg1, Bs[0] + ld1);

    int buf = 0;
    for (int k0 = 0; k0 < C_DIM; k0 += 32) {
        __syncthreads();   // drains vmcnt -> buf[k] ready; prior reads of buf^1 done
        if (k0 + 32 < C_DIM) {
            const int kn = k0 + 32, nb = buf ^ 1;
            async_ld16(ag0 + kn, As[nb] + ld0);
            async_ld16(ag1 + kn, As[nb] + ld1);
            async_ld16(bg0 + kn, Bs[nb] + ld0);
            async_ld16(bg1 + kn, Bs[nb] + ld1);
        }

        const ushort* Ab = As[buf];
        const ushort* Bb = Bs[buf];
        short8 af[4], bfr[4];
        #pragma unroll
        for (int mt = 0; mt < 4; ++mt)
            af[mt] = *(const short8*)(Ab + a_off + mt * 16 * 32);
        #pragma unroll
        for (int nt = 0; nt < 4; ++nt)
            bfr[nt] = *(const short8*)(Bb + b_off + nt * 16 * 32);
        #pragma unroll
        for (int mt = 0; mt < 4; ++mt)
            #pragma unroll
            for (int nt = 0; nt < 4; ++nt)
                acc[mt][nt] = __builtin_amdgcn_mfma_f32_16x16x32_bf16(
                    af[mt], bfr[nt], acc[mt][nt], 0, 0, 0);
        buf ^= 1;
    }

    // epilogue: per-row max over this block's 128 columns.
    // C/D layout: col = lane&15, row = (lane>>4)*4 + reg.
    #pragma unroll
    for (int mt = 0; mt < 4; ++mt) {
        #pragma unroll
        for (int reg = 0; reg < 4; ++reg) {
            float v = fmaxf(fmaxf(acc[mt][0][reg], acc[mt][1][reg]),
                            fmaxf(acc[mt][2][reg], acc[mt][3][reg]));
            #pragma unroll
            for (int off = 1; off < 16; off <<= 1)
                v = fmaxf(v, __shfl_xor(v, off, 64));
            if ((lane & 15) == 0) {
                int m = m0 + wm * 64 + mt * 16 + (lane >> 4) * 4 + reg;
                unsigned u = __float_as_uint(v);
                u = (u & 0x80000000u) ? ~u : (u | 0x80000000u);  // order-preserving
                atomicMax(&rowkey[m], u);
            }
        }
    }
}

// ---------------------------------------------------------------------------
// Final: loss = 1 - mean(rowmax)
// ---------------------------------------------------------------------------
__global__ __launch_bounds__(1024) void finalize(const unsigned* __restrict__ rowkey,
                                                 float* __restrict__ out) {
    const int t = threadIdx.x;
    float s = 0.f;
    for (int i = t; i < N_DIM; i += 1024) {
        unsigned u = rowkey[i];
        float f = (u & 0x80000000u) ? __uint_as_float(u ^ 0x80000000u)
                                    : __uint_as_float(~u);
        s += f;
    }
    #pragma unroll
    for (int off = 32; off >= 1; off >>= 1)
        s += __shfl_down(s, off, 64);
    __shared__ float part[16];
    if ((t & 63) == 0) part[t >> 6] = s;
    __syncthreads();
    if (t == 0) {
        float tot = 0.f;
        #pragma unroll
        for (int i = 0; i < 16; ++i) tot += part[i];
        out[0] = 1.0f - tot * (1.0f / (float)N_DIM);
    }
}

extern "C" void kernel_launch(void* const* d_in, const int* in_sizes, int n_in,
                              void* d_out, int out_size, void* d_ws, size_t ws_size,
                              hipStream_t stream) {
    const float* F_r = (const float*)d_in[0];
    const float* F_s = (const float*)d_in[1];

    ushort*   Rt     = (ushort*)d_ws;                       // 16384 x 768 bf16
    ushort*   St     = Rt + (size_t)N_DIM * C_DIM;          // 16384 x 768 bf16
    unsigned* rowkey = (unsigned*)(St + (size_t)N_DIM * C_DIM);  // 16384 u32
    float*    out    = (float*)d_out;

    hipLaunchKernelGGL(norm_tr, dim3(N_DIM / 64, 2), dim3(256), 0, stream,
                       F_r, Rt, F_s, St);
    hipMemsetAsync(rowkey, 0, N_DIM * sizeof(unsigned), stream);
    hipLaunchKernelGGL(gemm_rowmax, dim3(N_DIM / 128 * N_DIM / 128), dim3(256),
                       0, stream, Rt, St, rowkey);
    hipLaunchKernelGGL(finalize, dim3(1), dim3(1024), 0, stream, rowkey, out);
}

// Round 5
// 691.975 us; speedup vs baseline: 2.0667x; 1.0013x over previous
//
#include <hip/hip_runtime.h>
#include <cstdint>
#include <cstddef>

#define C_DIM 768
#define N_DIM 16384

typedef __attribute__((ext_vector_type(8))) short short8;   // 8 bf16 = 4 VGPRs
typedef __attribute__((ext_vector_type(4))) float f32x4;

__device__ __forceinline__ ushort f2bf(float f) {
    uint32_t u = __float_as_uint(f);
    uint32_t r = 0x7fffu + ((u >> 16) & 1u);   // round-to-nearest-even
    return (ushort)((u + r) >> 16);
}

__device__ __forceinline__ void async_ld16(const void* g, void* l) {
    __builtin_amdgcn_global_load_lds(
        (__attribute__((address_space(1))) void*)g,
        (__attribute__((address_space(3))) void*)l,
        16, 0, 0);
}

// ---------------------------------------------------------------------------
// Normalize columns of F (C_DIM x N_DIM) and write transposed bf16:
// T[i][c] = F[c][i] / max(||col_i||, eps).  blockIdx.y selects the input.
// (verified rounds 1-4)
// ---------------------------------------------------------------------------
__global__ __launch_bounds__(256) void norm_tr(const float* __restrict__ F0,
                                               ushort* __restrict__ T0,
                                               const float* __restrict__ F1,
                                               ushort* __restrict__ T1) {
    const float*  F = blockIdx.y ? F1 : F0;
    ushort*       T = blockIdx.y ? T1 : T0;
    const int i0 = blockIdx.x * 64;
    const int t  = threadIdx.x;
    const int tx = t & 63;
    const int ty = t >> 6;

    float ss = 0.f;
    for (int c = ty; c < C_DIM; c += 4) {
        float v = F[(size_t)c * N_DIM + i0 + tx];
        ss += v * v;
    }
    __shared__ float red[4][64];
    __shared__ float scale[64];
    red[ty][tx] = ss;
    __syncthreads();
    if (t < 64) {
        float s = red[0][t] + red[1][t] + red[2][t] + red[3][t];
        float n = sqrtf(s);
        scale[t] = 1.0f / fmaxf(n, 1e-12f);
    }
    __syncthreads();

    __shared__ float tile[64][65];
    const int i_l   = t >> 3;
    const int c_off = (t & 7) * 8;
    for (int c0 = 0; c0 < C_DIM; c0 += 64) {
        #pragma unroll
        for (int rr = 0; rr < 16; ++rr) {
            int c_l = rr * 4 + ty;
            tile[c_l][tx] = F[(size_t)(c0 + c_l) * N_DIM + i0 + tx] * scale[tx];
        }
        __syncthreads();
        #pragma unroll
        for (int half = 0; half < 2; ++half) {
            int il = i_l + half * 32;
            __align__(16) ushort pack[8];
            #pragma unroll
            for (int j = 0; j < 8; ++j)
                pack[j] = f2bf(tile[c_off + j][il]);
            *(uint4*)&T[(size_t)(i0 + il) * C_DIM + c0 + c_off] = *(const uint4*)pack;
        }
        __syncthreads();
    }
}

// ---------------------------------------------------------------------------
// Fused GEMM + row-max.  Round-4 core (bf16 16x16x32, BK=32, dbuf LDS with
// one barrier/iter, XOR bank swizzle = 0 conflicts, XCD-aware n-slicing)
// widened to a 128x256 block tile with 512 threads / 8 waves:
//   - each wave still computes 64x64 (4x4 subtiles) -> VGPR stays ~64
//   - B tile (256 rows) staged ONCE per iter serves 2x the FLOPs: per-FLOP
//     barrier/sync cost halves vs round 4
//   - LDS = (8KB A + 16KB B) x 2 buffers = 48 KB -> 3 blocks/CU,
//     24 waves/CU = 75% occupancy (round 4: 45%)
// ---------------------------------------------------------------------------
__global__ __launch_bounds__(512) void gemm_rowmax(const ushort* __restrict__ A,
                                                   const ushort* __restrict__ B,
                                                   unsigned* __restrict__ rowkey) {
    __shared__ __align__(16) ushort As[2][128 * 32];   // 16 KB
    __shared__ __align__(16) ushort Bs[2][256 * 32];   // 32 KB

    const int t    = threadIdx.x;
    const int lane = t & 63;
    const int w    = t >> 6;          // 0..7
    const int wm   = w >> 2;          // 0..1  (64-row half)
    const int wn   = w & 3;           // 0..3  (64-col quarter)

    // XCD-aware mapping: xcd owns an 8-tile n-slice (2048 cols, 3MB of B in
    // its L2); n fastest so A-tiles get 8x L2 reuse across consecutive blocks.
    const int bid   = blockIdx.x;
    const int xcd   = bid & 7;
    const int local = bid >> 3;                     // 0..1023
    const int m0    = (local >> 3) * 128;           // 128 m-tiles
    const int n0    = (xcd * 8 + (local & 7)) * 256;

    f32x4 acc[4][4];
    #pragma unroll
    for (int i = 0; i < 4; ++i)
        #pragma unroll
        for (int j = 0; j < 4; ++j)
            acc[i][j] = (f32x4){0.f, 0.f, 0.f, 0.f};

    // staging: thread t -> row t>>2, phys 16B chunk t&3 at LDS byte t*16;
    // logical k-quad XOR-swizzled by row bits 1-2 (verified 0 conflicts).
    // B second issue covers rows 128..255: (row>>1)&3 == (t>>3)&3 still.
    const int kq = ((t & 3) ^ ((t >> 3) & 3)) * 8;
    const ushort* ag  = A + (size_t)(m0 + (t >> 2)) * C_DIM + kq;
    const ushort* bg0 = B + (size_t)(n0 + (t >> 2)) * C_DIM + kq;
    const ushort* bg1 = bg0 + (size_t)128 * C_DIM;
    const int lda = t * 8;                 // element offsets into As/Bs
    const int ldb0 = t * 8, ldb1 = 128 * 32 + t * 8;

    // fragment reads: logical k-quad x = lane>>4 lives at quadpos
    // x ^ ((row>>1)&3); row = base + (lane&15), base % 16 == 0.
    const int qp    = ((lane >> 4) ^ ((lane >> 1) & 3)) * 8;
    const int a_off = (wm * 64 + (lane & 15)) * 32 + qp;
    const int b_off = (wn * 64 + (lane & 15)) * 32 + qp;

    // prologue: stage k0=0 into buffer 0
    async_ld16(ag,  As[0] + lda);
    async_ld16(bg0, Bs[0] + ldb0);
    async_ld16(bg1, Bs[0] + ldb1);

    int buf = 0;
    for (int k0 = 0; k0 < C_DIM; k0 += 32) {
        __syncthreads();   // buf[k] staged; prior reads of buf^1 complete
        if (k0 + 32 < C_DIM) {
            const int kn = k0 + 32, nb = buf ^ 1;
            async_ld16(ag + kn,  As[nb] + lda);
            async_ld16(bg0 + kn, Bs[nb] + ldb0);
            async_ld16(bg1 + kn, Bs[nb] + ldb1);
        }

        const ushort* Ab = As[buf];
        const ushort* Bb = Bs[buf];
        short8 af[4], bfr[4];
        #pragma unroll
        for (int mt = 0; mt < 4; ++mt)
            af[mt] = *(const short8*)(Ab + a_off + mt * 16 * 32);
        #pragma unroll
        for (int nt = 0; nt < 4; ++nt)
            bfr[nt] = *(const short8*)(Bb + b_off + nt * 16 * 32);
        #pragma unroll
        for (int mt = 0; mt < 4; ++mt)
            #pragma unroll
            for (int nt = 0; nt < 4; ++nt)
                acc[mt][nt] = __builtin_amdgcn_mfma_f32_16x16x32_bf16(
                    af[mt], bfr[nt], acc[mt][nt], 0, 0, 0);
        buf ^= 1;
    }

    // epilogue: per-row max over this wave's 64 columns; waves sharing the
    // same m-rows (wn 0..3) merge via device-scope atomicMax.
    // C/D layout: col = lane&15, row = (lane>>4)*4 + reg.
    #pragma unroll
    for (int mt = 0; mt < 4; ++mt) {
        #pragma unroll
        for (int reg = 0; reg < 4; ++reg) {
            float v = fmaxf(fmaxf(acc[mt][0][reg], acc[mt][1][reg]),
                            fmaxf(acc[mt][2][reg], acc[mt][3][reg]));
            #pragma unroll
            for (int off = 1; off < 16; off <<= 1)
                v = fmaxf(v, __shfl_xor(v, off, 64));
            if ((lane & 15) == 0) {
                int m = m0 + wm * 64 + mt * 16 + (lane >> 4) * 4 + reg;
                unsigned u = __float_as_uint(v);
                u = (u & 0x80000000u) ? ~u : (u | 0x80000000u);  // order-preserving
                atomicMax(&rowkey[m], u);
            }
        }
    }
}

// ---------------------------------------------------------------------------
// Final: loss = 1 - mean(rowmax)
// ---------------------------------------------------------------------------
__global__ __launch_bounds__(1024) void finalize(const unsigned* __restrict__ rowkey,
                                                 float* __restrict__ out) {
    const int t = threadIdx.x;
    float s = 0.f;
    for (int i = t; i < N_DIM; i += 1024) {
        unsigned u = rowkey[i];
        float f = (u & 0x80000000u) ? __uint_as_float(u ^ 0x80000000u)
                                    : __uint_as_float(~u);
        s += f;
    }
    #pragma unroll
    for (int off = 32; off >= 1; off >>= 1)
        s += __shfl_down(s, off, 64);
    __shared__ float part[16];
    if ((t & 63) == 0) part[t >> 6] = s;
    __syncthreads();
    if (t == 0) {
        float tot = 0.f;
        #pragma unroll
        for (int i = 0; i < 16; ++i) tot += part[i];
        out[0] = 1.0f - tot * (1.0f / (float)N_DIM);
    }
}

extern "C" void kernel_launch(void* const* d_in, const int* in_sizes, int n_in,
                              void* d_out, int out_size, void* d_ws, size_t ws_size,
                              hipStream_t stream) {
    const float* F_r = (const float*)d_in[0];
    const float* F_s = (const float*)d_in[1];

    ushort*   Rt     = (ushort*)d_ws;                       // 16384 x 768 bf16
    ushort*   St     = Rt + (size_t)N_DIM * C_DIM;          // 16384 x 768 bf16
    unsigned* rowkey = (unsigned*)(St + (size_t)N_DIM * C_DIM);  // 16384 u32
    float*    out    = (float*)d_out;

    hipLaunchKernelGGL(norm_tr, dim3(N_DIM / 64, 2), dim3(256), 0, stream,
                       F_r, Rt, F_s, St);
    hipMemsetAsync(rowkey, 0, N_DIM * sizeof(unsigned), stream);
    hipLaunchKernelGGL(gemm_rowmax, dim3((N_DIM / 128) * (N_DIM / 256)), dim3(512),
                       0, stream, Rt, St, rowkey);
    hipLaunchKernelGGL(finalize, dim3(1), dim3(1024), 0, stream, rowkey, out);
}